// Round 16
// baseline (232.721 us; speedup 1.0000x reference)
//
#include <hip/hip_runtime.h>
#include <hip/hip_bf16.h>
#include <cstdint>
#include <cstddef>

using u16 = unsigned short;
typedef __bf16 bf16x8 __attribute__((ext_vector_type(8)));
typedef float f32x4 __attribute__((ext_vector_type(4)));
typedef float f32x16 __attribute__((ext_vector_type(16)));
typedef u16 u16x4 __attribute__((ext_vector_type(4)));
typedef u16 u16x8 __attribute__((ext_vector_type(8)));
typedef uint32_t u32x2 __attribute__((ext_vector_type(2)));
typedef uint32_t u32x4 __attribute__((ext_vector_type(4)));

__device__ __forceinline__ u16 f2bf(float f) {
  uint32_t u = __builtin_bit_cast(uint32_t, f);
  u += 0x7FFFu + ((u >> 16) & 1u);   // RNE
  return (u16)(u >> 16);
}

__device__ __forceinline__ void gld_lds16(const void* g, void* l) {
  __builtin_amdgcn_global_load_lds(
      (const __attribute__((address_space(1))) unsigned int*)g,
      (__attribute__((address_space(3))) unsigned int*)l, 16, 0, 0);
}

#define MFMA16(a, b, c) __builtin_amdgcn_mfma_f32_16x16x32_bf16((a), (b), (c), 0, 0, 0)
#define MFMA32(a, b, c) __builtin_amdgcn_mfma_f32_32x32x16_bf16((a), (b), (c), 0, 0, 0)

__device__ __forceinline__ uint32_t pkbf(float a, float b) {
  uint32_t d;
  asm("v_cvt_pk_bf16_f32 %0, %1, %2" : "=v"(d) : "v"(a), "v"(b));
  return d;
}
__device__ __forceinline__ void swap32(uint32_t& a, uint32_t& b) {
  asm volatile("v_permlane32_swap_b32 %0, %1" : "+v"(a), "+v"(b));
}
__device__ __forceinline__ bf16x8 mk8(u32x2 a, u32x2 b) {
  return __builtin_bit_cast(bf16x8, u32x4{a[0], a[1], b[0], b[1]});
}

// ---------------- fp32 -> bf16 converts ----------------
__global__ void cvt_kernel(const float* __restrict__ in, u16* __restrict__ out, int n4) {
  int i = blockIdx.x * blockDim.x + threadIdx.x;
  int stride = gridDim.x * blockDim.x;
  for (; i < n4; i += stride) {
    float4 v = reinterpret_cast<const float4*>(in)[i];
    u16x4 o;
    o[0] = f2bf(v.x); o[1] = f2bf(v.y); o[2] = f2bf(v.z); o[3] = f2bf(v.w);
    reinterpret_cast<u16x4*>(out)[i] = o;
  }
}

__global__ void cvt4_kernel(const float* __restrict__ x, const float* __restrict__ Wq,
                            const float* __restrict__ Wk, const float* __restrict__ Wv,
                            u16* __restrict__ xb, u16* __restrict__ Wc) {
  int i = blockIdx.x * blockDim.x + threadIdx.x;
  int stride = gridDim.x * blockDim.x;
  for (; i < 3670016; i += stride) {
    const float* src; u16* dst; int off;
    if (i < 2097152)      { src = x;  dst = xb;            off = i; }
    else if (i < 3145728) { src = Wq; dst = Wc;            off = i - 2097152; }
    else if (i < 3407872) { src = Wk; dst = Wc + 4194304;  off = i - 3145728; }
    else                  { src = Wv; dst = Wc + 5242880;  off = i - 3407872; }
    float4 v = reinterpret_cast<const float4*>(src)[off];
    u16x4 o;
    o[0] = f2bf(v.x); o[1] = f2bf(v.y); o[2] = f2bf(v.z); o[3] = f2bf(v.w);
    reinterpret_cast<u16x4*>(dst)[off] = o;
  }
}

// ---------------- bf16 GEMM (R11 verbatim: m97 core + T3/T4 pipeline + T1 swizzle) ----------------
template <bool OUT_BF16>
__global__ __launch_bounds__(256) void gemm_bt(const u16* __restrict__ A,
                                               const u16* __restrict__ B,
                                               void* __restrict__ Cv,
                                               int M, int N, int K) {
  __shared__ __align__(16) u16 Ash[3][128 * 32];
  __shared__ __align__(16) u16 Bsh[3][128 * 32];
  const int tid = threadIdx.x;
  const int w = tid >> 6, lane = tid & 63, ql = lane & 15, g = lane >> 4;
  const int wr = w >> 1, wc = w & 1;
  const int bid = blockIdx.y * gridDim.x + blockIdx.x;
  const int nwg = gridDim.x * gridDim.y;
  const int wg = (bid & 7) * (nwg >> 3) + (bid >> 3);
  const int m0 = (wg / gridDim.x) * 128, n0 = (wg % gridDim.x) * 128;
  const int srow = w * 16 + (lane >> 2);
  const int sk = (lane & 3) * 8;
  const u16* Abase = A + (size_t)(m0 + srow) * K + sk;
  const u16* Bbase = B + (size_t)(n0 + srow) * K + sk;

  f32x4 acc[4][4];
#pragma unroll
  for (int i = 0; i < 4; i++)
#pragma unroll
    for (int j = 0; j < 4; j++) acc[i][j] = f32x4{0.f, 0.f, 0.f, 0.f};

  auto stage = [&](int bi, int tile) {
    const int kt = tile * 32;
    gld_lds16(Abase + kt,                  &Ash[bi][w * 512]);
    gld_lds16(Abase + (size_t)64 * K + kt, &Ash[bi][2048 + w * 512]);
    gld_lds16(Bbase + kt,                  &Bsh[bi][w * 512]);
    gld_lds16(Bbase + (size_t)64 * K + kt, &Bsh[bi][2048 + w * 512]);
  };

  const int nt = K >> 5;
  stage(0, 0);
  stage(1, 1);
  asm volatile("s_waitcnt vmcnt(4)" ::: "memory");
  __builtin_amdgcn_sched_barrier(0);
  __builtin_amdgcn_s_barrier();
  __builtin_amdgcn_sched_barrier(0);

  int cur = 0;
  for (int t = 0; t < nt; ++t) {
    if (t + 2 < nt) {
      int stg = cur + 2; if (stg >= 3) stg -= 3;
      stage(stg, t + 2);
    }
    bf16x8 af[4], bfr[4];
#pragma unroll
    for (int i = 0; i < 4; i++)
      af[i] = *reinterpret_cast<const bf16x8*>(&Ash[cur][(wr * 64 + i * 16 + ql) * 32 + g * 8]);
#pragma unroll
    for (int j = 0; j < 4; j++)
      bfr[j] = *reinterpret_cast<const bf16x8*>(&Bsh[cur][(wc * 64 + j * 16 + ql) * 32 + g * 8]);
    __builtin_amdgcn_s_setprio(1);
#pragma unroll
    for (int i = 0; i < 4; i++)
#pragma unroll
      for (int j = 0; j < 4; j++)
        acc[i][j] = MFMA16(af[i], bfr[j], acc[i][j]);
    __builtin_amdgcn_s_setprio(0);
    if (t + 1 < nt) {
      if (t + 2 < nt) {
        asm volatile("s_waitcnt vmcnt(4)" ::: "memory");
      } else {
        asm volatile("s_waitcnt vmcnt(0)" ::: "memory");
      }
      __builtin_amdgcn_sched_barrier(0);
      __builtin_amdgcn_s_barrier();
      __builtin_amdgcn_sched_barrier(0);
    }
    cur = (cur == 2) ? 0 : cur + 1;
  }

#pragma unroll
  for (int i = 0; i < 4; i++)
#pragma unroll
    for (int j = 0; j < 4; j++)
#pragma unroll
      for (int r = 0; r < 4; r++) {
        const int row = m0 + wr * 64 + i * 16 + g * 4 + r;
        const int col = n0 + wc * 64 + j * 16 + ql;
        if constexpr (OUT_BF16)
          ((u16*)Cv)[(size_t)row * N + col] = f2bf(acc[i][j][r]);
        else
          ((float*)Cv)[(size_t)row * N + col] = acc[i][j][r];
      }
}

// ---------------- flash attention v10: KVBLK=32 + triple-buffer counted-vmcnt ----------------
// T3/T4 ported from the GEMM: stage tile t+2 / compute t%3 / vmcnt(4) + raw
// s_barrier (never drain to 0 in-loop). V layout becomes 8x[32][16] (s21's
// conflict-free tr shape), dg-stride 520 u16. Static-m softmax (R15), ones-lacc,
// tr-read PV. LDS ~50KB -> 2 blocks/CU.
#define TRRD(D, B, IMM) \
  asm volatile("ds_read_b64_tr_b16 %0, %1 offset:" #IMM : "=v"(D) : "v"(B))

#define PV_CLUSTER(PF, O0, O1, O2, O3, O4, O5, O6, O7)                          \
  do {                                                                          \
    u32x2 a0, a1, b0, b1, c0, c1, d0, d1;                                       \
    TRRD(a0, ab, O0); TRRD(a1, ab, O1); TRRD(b0, ab, O2); TRRD(b1, ab, O3);     \
    TRRD(c0, ab, O4); TRRD(c1, ab, O5); TRRD(d0, ab, O6); TRRD(d1, ab, O7);     \
    asm volatile("s_waitcnt lgkmcnt(0)" ::: "memory");                          \
    __builtin_amdgcn_sched_barrier(0);                                          \
    __builtin_amdgcn_s_setprio(1);                                              \
    oacc[0] = MFMA32(PF, mk8(a0, a1), oacc[0]);                                 \
    oacc[1] = MFMA32(PF, mk8(b0, b1), oacc[1]);                                 \
    oacc[2] = MFMA32(PF, mk8(c0, c1), oacc[2]);                                 \
    oacc[3] = MFMA32(PF, mk8(d0, d1), oacc[3]);                                 \
    __builtin_amdgcn_s_setprio(0);                                              \
  } while (0)

__global__ __launch_bounds__(256, 2) void attn_kernel(const u16* __restrict__ QKV,
                                                      u16* __restrict__ O) {
  __shared__ __align__(16) u16 SHK[3 * 4096];   // 3 bufs [32 s][128 k], slot16 ^= (s&7)
  __shared__ __align__(16) u16 SHV[3 * 4160];   // 3 bufs [8 dg][32 s][16 dr], dg-stride 520
  __shared__ float lbuf[4][32];
  const int tid = threadIdx.x, w = tid >> 6, lane = tid & 63;
  const int lq = lane & 31, hi = lane >> 5;
  const int bid = blockIdx.x;
  const int swz = (bid & 7) * 64 + (bid >> 3);
  const int qt = swz & 15;
  const int bh = swz >> 4;
  const int b = bh >> 4, h = bh & 15, hkv = h >> 2;
  const size_t rowb = (size_t)b * 2048;
  const int qbase = qt * 128 + w * 32;

  const u16* Kg = QKV + 2048 + hkv * 128;
  const u16* Vg = QKV + 2560 + hkv * 128;

  bf16x8 bq[8];
  {
    const u16* qp = QKV + (rowb + qbase + lq) * 3072 + h * 128 + hi * 8;
#pragma unroll
    for (int s5 = 0; s5 < 8; s5++)
      bq[s5] = *reinterpret_cast<const bf16x8*>(qp + s5 * 16);
  }

  f32x16 oacc[4], lacc;
#pragma unroll
  for (int dt = 0; dt < 4; dt++)
#pragma unroll
    for (int i = 0; i < 16; i++) oacc[dt][i] = 0.f;
#pragma unroll
  for (int i = 0; i < 16; i++) lacc[i] = 0.f;
  const float CEXP = 0.08838834764831845f * 1.4426950408889634f;  // scale*log2e

  const bf16x8 ones = __builtin_bit_cast(bf16x8,
      u32x4{0x3F803F80u, 0x3F803F80u, 0x3F803F80u, 0x3F803F80u});

  // K stage: 2 gld_lds/thread per tile (8KB tile).
  auto stageK = [&](int kb, int sbase) {
#pragma unroll
    for (int p = 0; p < 2; p++) {
      const int L = p * 2048 + tid * 8;
      const int s = L >> 7;
      const int gI = (L >> 3) & 15;
      gld_lds16(Kg + (rowb + sbase + s) * 3072 + ((gI ^ (s & 7)) << 3),
                &SHK[kb * 4096 + p * 2048 + w * 512]);
    }
  };
  // V stage: 2 gld_lds/thread; one instr covers one dg block (32s x 16dr = 1KB).
  auto stageV = [&](int vb, int sbase) {
#pragma unroll
    for (int c = 0; c < 2; c++) {
      const int dg = w * 2 + c;
      const int s = lane >> 1;
      const int dr0 = (lane & 1) * 8;
      gld_lds16(Vg + (rowb + sbase + s) * 3072 + dg * 16 + dr0,
                &SHV[vb * 4160 + dg * 520]);
    }
  };

#define KFRAG(PB, S5) \
  (*reinterpret_cast<const bf16x8*>(&SHK[(PB)*4096 + lq * 128 + ((((S5)*2 + hi) ^ (lq & 7)) << 3)]))

  // tr base (bytes): colhalf -> dg parity (520 u16 = 1040B), hi -> +8 rows (256B),
  // lane&15 walks the group's contiguous 128B tile.
  const uint32_t vbase0 =
      (uint32_t)(uintptr_t)(__attribute__((address_space(3))) u16*)&SHV[0];
  const uint32_t vlane = vbase0 + ((lane >> 4) & 1) * 1040u + (lane >> 5) * 256u
                       + (lane & 15) * 8u;

  // ---- prologue: stage tiles 0,1 ----
  stageK(0, 0);
  stageV(0, 0);
  stageK(1, 32);
  stageV(1, 32);
  asm volatile("s_waitcnt vmcnt(4)" ::: "memory");
  __builtin_amdgcn_sched_barrier(0);
  __builtin_amdgcn_s_barrier();
  __builtin_amdgcn_sched_barrier(0);

  int cur = 0;
#pragma unroll 1
  for (int t = 0; t < 64; ++t) {
    if (t + 2 < 64) {
      int stg = cur + 2; if (stg >= 3) stg -= 3;
      stageK(stg, (t + 2) * 32);
      stageV(stg, (t + 2) * 32);
    }

    // ---- S^T = K @ Q^T (one 32x32 tile) ----
    f32x16 sc;
#pragma unroll
    for (int i = 0; i < 16; i++) sc[i] = 0.f;
    __builtin_amdgcn_s_setprio(1);
#pragma unroll
    for (int s5 = 0; s5 < 8; s5++)
      sc = MFMA32(KFRAG(cur, s5), bq[s5], sc);
    __builtin_amdgcn_s_setprio(0);

    // ---- static-m softmax ----
    float e[16];
#pragma unroll
    for (int i = 0; i < 16; i++) e[i] = exp2f(sc[i] * CEXP);
    bf16x8 pf0, pf1;
    {
      uint32_t a, bw;
      u32x4 f;
      a = pkbf(e[0], e[1]);   bw = pkbf(e[4], e[5]);   swap32(a, bw);
      f[0] = a; f[2] = bw;
      a = pkbf(e[2], e[3]);   bw = pkbf(e[6], e[7]);   swap32(a, bw);
      f[1] = a; f[3] = bw;
      pf0 = __builtin_bit_cast(bf16x8, f);
      a = pkbf(e[8], e[9]);   bw = pkbf(e[12], e[13]); swap32(a, bw);
      f[0] = a; f[2] = bw;
      a = pkbf(e[10], e[11]); bw = pkbf(e[14], e[15]); swap32(a, bw);
      f[1] = a; f[3] = bw;
      pf1 = __builtin_bit_cast(bf16x8, f);
    }

    // ---- row-sum via ones-MFMA ----
    lacc = MFMA32(ones, pf0, lacc);
    lacc = MFMA32(ones, pf1, lacc);

    // ---- PV: O[q][d] += P^T @ V (B via hw transpose read) ----
    // imm = dt*2080 + ks*512 + jj*128
    {
      const uint32_t ab = vlane + (uint32_t)(cur * 8320);
      PV_CLUSTER(pf0, 0, 128, 2080, 2208, 4160, 4288, 6240, 6368);
      PV_CLUSTER(pf1, 512, 640, 2592, 2720, 4672, 4800, 6752, 6880);
    }

    if (t + 1 < 64) {
      if (t + 2 < 64) {
        asm volatile("s_waitcnt vmcnt(4)" ::: "memory");
      } else {
        asm volatile("s_waitcnt vmcnt(0)" ::: "memory");
      }
      __builtin_amdgcn_sched_barrier(0);
      __builtin_amdgcn_s_barrier();
      __builtin_amdgcn_sched_barrier(0);
    }
    cur = (cur == 2) ? 0 : cur + 1;
  }
  __syncthreads();  // all reads done before epilogue reuses LDS

  // ---- epilogue: spread l (indexed by q), normalize rows, LDS transpose, store ----
  if (hi == 0) lbuf[w][lq] = lacc[0];
  __syncthreads();
  u16* ob = (w < 2) ? &SHK[w * 4352] : &SHV[(w - 2) * 4352];
#pragma unroll
  for (int dt = 0; dt < 4; dt++)
#pragma unroll
    for (int r = 0; r < 16; r++) {
      const int qr = (r & 3) + 8 * (r >> 2) + 4 * hi;
      ob[qr * 136 + dt * 32 + lq] = f2bf(oacc[dt][r] * (1.0f / lbuf[w][qr]));
    }
  const int orow = lane >> 1, och = (lane & 1) * 64;
  u16* og = O + (rowb + qbase + orow) * 2048 + h * 128 + och;
#pragma unroll
  for (int t = 0; t < 8; t++) {
    u16x8 v = *reinterpret_cast<const u16x8*>(&ob[orow * 136 + och + t * 8]);
    *reinterpret_cast<u16x8*>(og + t * 8) = v;
  }
#undef KFRAG
}

// ---------------- launch ----------------
extern "C" void kernel_launch(void* const* d_in, const int* in_sizes, int n_in,
                              void* d_out, int out_size, void* d_ws, size_t ws_size,
                              hipStream_t stream) {
  (void)in_sizes; (void)n_in; (void)out_size;
  const float* x  = (const float*)d_in[0];
  const float* Wq = (const float*)d_in[1];
  const float* Wk = (const float*)d_in[2];
  const float* Wv = (const float*)d_in[3];
  const float* Wo = (const float*)d_in[4];

  if (ws_size < (size_t)(8388608 + 6291456 + 12582912) * 2) return;
  u16* xb  = (u16*)d_ws;
  u16* Wc  = xb + 8388608;
  u16* QKV = Wc + 6291456;
  u16* Ob  = xb;  // reuse x-bf16 region for attention output

  cvt4_kernel<<<2048, 256, 0, stream>>>(x, Wq, Wk, Wv, xb, Wc);
  gemm_bt<true><<<dim3(24, 32), 256, 0, stream>>>(xb, Wc, (void*)QKV, 4096, 3072, 2048);
  cvt_kernel<<<2048, 256, 0, stream>>>(Wo, Wc, 1048576);
  attn_kernel<<<dim3(512), 256, 0, stream>>>(QKV, Ob);
  gemm_bt<false><<<dim3(16, 32), 256, 0, stream>>>(Ob, Wc, d_out, 4096, 2048, 2048);
}